// Round 3
// baseline (849.446 us; speedup 1.0000x reference)
//
#include <hip/hip_runtime.h>
#include <hip/hip_cooperative_groups.h>

namespace cg = cooperative_groups;

// CrossNet fused: B=16384, D=1024, 4 layers of
//   s = res.w ; res = res + x0*s + b ; res = BN_batch(res)
//
// Primary path: ONE cooperative kernel, res resident in VGPRs all 4 layers.
//  - 256 blocks x 512 threads (1 block/CU -> cooperative co-residency trivially
//    satisfied). Block = 2 halves x 256 col-threads; a half owns 32 rows,
//    thread owns cols [4t,4t+4) (float4 loads). res[32] = 128 VGPRs.
//  - BN carried as lazy per-column (scale,shift), applied in-register.
//  - Stats: per-half partials (512,D) -> grid.sync -> 64 blocks reduce ->
//    grid.sync. 2 grid syncs/layer.
// Fallback path (if cooperative launch is rejected): the verified R1
// multi-kernel pipeline. kernel_launch checks the launch error.

#define BB 16384
#define DD 1024
#define NL 4
#define BN_EPS 1e-5f

// ---------------- cooperative fused path ----------------
constexpr int CGRID = 256;
constexpr int CTPB  = 512;           // 2 halves x 256 col-threads
constexpr int CRPB  = BB / CGRID;    // 64 rows per block
constexpr int CRPT  = CRPB / 2;      // 32 rows per half
constexpr int GRP   = 8;             // rows per dot-reduce batch
constexpr int NGRP  = CRPT / GRP;    // 4
constexpr int PROWS = CGRID * 2;     // 512 partial-stat rows

__global__ __launch_bounds__(CTPB, 2) void crossnet_coop(
    const float* __restrict__ x,     // (B,D)
    const float* __restrict__ ww,    // (NL,D)
    const float* __restrict__ wb,    // (NL,D)
    float* __restrict__ out,         // (B,D)
    float* __restrict__ Psum,        // (PROWS,D) ws
    float* __restrict__ Psq,         // (PROWS,D) ws
    float* __restrict__ scale,       // (D) ws
    float* __restrict__ shift)       // (D) ws
{
    cg::grid_group grid = cg::this_grid();
    __shared__ float red[2][GRP][8];   // [slot][row][wave]
    __shared__ float sA[32][16];
    __shared__ float sQ[32][16];

    const int t    = threadIdx.x;
    const int lane = t & 63;
    const int wv   = t >> 6;           // wave 0..7
    const int half = wv >> 2;          // 0 or 1 (wave fully inside a half)
    const int c    = (t & 255) << 2;   // this thread's 4 columns
    const int b    = blockIdx.x;
    const int r0   = b * CRPB + half * CRPT;

    float4 res[CRPT];
    #pragma unroll
    for (int r = 0; r < CRPT; ++r)
        res[r] = *(const float4*)(x + (size_t)(r0 + r) * DD + c);

    float4 sc4 = make_float4(1.f, 1.f, 1.f, 1.f);
    float4 sh4 = make_float4(0.f, 0.f, 0.f, 0.f);

    for (int l = 0; l < NL; ++l) {
        const float4 w4 = *(const float4*)(ww + (size_t)l * DD + c);
        const float4 b4 = *(const float4*)(wb + (size_t)l * DD + c);

        if (l > 0) {
            #pragma unroll
            for (int r = 0; r < CRPT; ++r) {
                res[r].x = fmaf(res[r].x, sc4.x, sh4.x);
                res[r].y = fmaf(res[r].y, sc4.y, sh4.y);
                res[r].z = fmaf(res[r].z, sc4.z, sh4.z);
                res[r].w = fmaf(res[r].w, sc4.w, sh4.w);
            }
        }

        float4 asum = make_float4(0.f, 0.f, 0.f, 0.f);
        float4 asq  = make_float4(0.f, 0.f, 0.f, 0.f);

        for (int g = 0; g < NGRP; ++g) {
            float4 xg[GRP];
            if (l > 0) {
                #pragma unroll
                for (int j = 0; j < GRP; ++j)
                    xg[j] = *(const float4*)(x + (size_t)(r0 + g * GRP + j) * DD + c);
            }

            float p[GRP];
            #pragma unroll
            for (int j = 0; j < GRP; ++j) {
                const float4 v = res[g * GRP + j];
                p[j] = v.x * w4.x + v.y * w4.y + v.z * w4.z + v.w * w4.w;
            }
            #pragma unroll
            for (int off = 32; off; off >>= 1) {
                #pragma unroll
                for (int j = 0; j < GRP; ++j)
                    p[j] += __shfl_down(p[j], off, 64);
            }
            const int slot = g & 1;
            if (lane == 0) {
                #pragma unroll
                for (int j = 0; j < GRP; ++j) red[slot][j][wv] = p[j];
            }
            __syncthreads();

            const int w0 = half << 2;  // my half's 4 waves
            #pragma unroll
            for (int j = 0; j < GRP; ++j) {
                const float s = red[slot][j][w0] + red[slot][j][w0 + 1] +
                                red[slot][j][w0 + 2] + red[slot][j][w0 + 3];
                const float4 v  = res[g * GRP + j];
                const float4 xv = (l == 0) ? v : xg[j];
                float4 n;
                n.x = fmaf(xv.x, s, v.x) + b4.x;
                n.y = fmaf(xv.y, s, v.y) + b4.y;
                n.z = fmaf(xv.z, s, v.z) + b4.z;
                n.w = fmaf(xv.w, s, v.w) + b4.w;
                res[g * GRP + j] = n;
                asum.x += n.x; asum.y += n.y; asum.z += n.z; asum.w += n.w;
                asq.x = fmaf(n.x, n.x, asq.x);
                asq.y = fmaf(n.y, n.y, asq.y);
                asq.z = fmaf(n.z, n.z, asq.z);
                asq.w = fmaf(n.w, n.w, asq.w);
            }
        }

        const int prow = (b << 1) + half;
        *(float4*)(Psum + (size_t)prow * DD + c) = asum;
        *(float4*)(Psq  + (size_t)prow * DD + c) = asq;
        __threadfence();
        grid.sync();

        // 64 blocks: block b handles columns [16b, 16b+16) over 512 partials.
        if (b < 64) {
            const int cl  = (b << 4) + (t & 15);
            const int seg = t >> 4;                    // 0..31
            float s = 0.f, q = 0.f;
            #pragma unroll
            for (int r = seg * (PROWS / 32); r < (seg + 1) * (PROWS / 32); ++r) {
                s += Psum[(size_t)r * DD + cl];
                q += Psq[(size_t)r * DD + cl];
            }
            sA[seg][t & 15] = s;
            sQ[seg][t & 15] = q;
            __syncthreads();
            if (t < 16) {
                float ss = 0.f, qq = 0.f;
                #pragma unroll
                for (int k = 0; k < 32; ++k) { ss += sA[k][t]; qq += sQ[k][t]; }
                const float mu  = ss * (1.0f / BB);
                const float var = qq * (1.0f / BB) - mu * mu;
                const float inv = rsqrtf(var + BN_EPS);
                scale[(b << 4) + t] = inv;
                shift[(b << 4) + t] = -mu * inv;
            }
            __threadfence();
        }
        grid.sync();

        sc4 = *(const float4*)(scale + c);
        sh4 = *(const float4*)(shift + c);
    }

    #pragma unroll
    for (int r = 0; r < CRPT; ++r) {
        float4 v = res[r];
        v.x = fmaf(v.x, sc4.x, sh4.x);
        v.y = fmaf(v.y, sc4.y, sh4.y);
        v.z = fmaf(v.z, sc4.z, sh4.z);
        v.w = fmaf(v.w, sc4.w, sh4.w);
        *(float4*)(out + (size_t)(r0 + r) * DD + c) = v;
    }
}

// ---------------- fallback multi-kernel path (verified in R1) ----------------
constexpr int ABLK = 1024;
constexpr int ROWS_PER_BLK = BB / ABLK;
constexpr int NB1 = 64;
constexpr int RED0 = ABLK / NB1;

template <bool FIRST>
__global__ __launch_bounds__(256) void layer_kernel(
    const float* __restrict__ x0, const float* Rin, float* Rout,
    const float* __restrict__ w, const float* __restrict__ bias,
    const float* __restrict__ scale, const float* __restrict__ shift,
    float* __restrict__ Psum, float* __restrict__ Psq)
{
    __shared__ float red[2][2][4];
    const int tid  = threadIdx.x;
    const int lane = tid & 63;
    const int wv   = tid >> 6;
    const int c    = tid << 2;

    const float4 w4 = *(const float4*)(w + c);
    const float4 b4 = *(const float4*)(bias + c);
    float4 sc4, sh4;
    if (FIRST) {
        sc4 = make_float4(1.f, 1.f, 1.f, 1.f);
        sh4 = make_float4(0.f, 0.f, 0.f, 0.f);
    } else {
        sc4 = *(const float4*)(scale + c);
        sh4 = *(const float4*)(shift + c);
    }

    float4 asum = make_float4(0.f, 0.f, 0.f, 0.f);
    float4 asq  = make_float4(0.f, 0.f, 0.f, 0.f);
    const int r0 = blockIdx.x * ROWS_PER_BLK;

    for (int it = 0; it < ROWS_PER_BLK / 2; ++it) {
        const int r = r0 + it * 2;
        const size_t base0 = (size_t)r * DD + c;
        const size_t base1 = base0 + DD;
        float4 v0 = *(const float4*)(Rin + base0);
        float4 v1 = *(const float4*)(Rin + base1);
        float4 xv0, xv1;
        if (!FIRST) {
            xv0 = *(const float4*)(x0 + base0);
            xv1 = *(const float4*)(x0 + base1);
        }
        v0.x = fmaf(v0.x, sc4.x, sh4.x); v0.y = fmaf(v0.y, sc4.y, sh4.y);
        v0.z = fmaf(v0.z, sc4.z, sh4.z); v0.w = fmaf(v0.w, sc4.w, sh4.w);
        v1.x = fmaf(v1.x, sc4.x, sh4.x); v1.y = fmaf(v1.y, sc4.y, sh4.y);
        v1.z = fmaf(v1.z, sc4.z, sh4.z); v1.w = fmaf(v1.w, sc4.w, sh4.w);
        if (FIRST) { xv0 = v0; xv1 = v1; }

        float p0 = v0.x * w4.x + v0.y * w4.y + v0.z * w4.z + v0.w * w4.w;
        float p1 = v1.x * w4.x + v1.y * w4.y + v1.z * w4.z + v1.w * w4.w;
        #pragma unroll
        for (int off = 32; off; off >>= 1) {
            p0 += __shfl_down(p0, off, 64);
            p1 += __shfl_down(p1, off, 64);
        }
        const int slot = it & 1;
        if (lane == 0) { red[slot][0][wv] = p0; red[slot][1][wv] = p1; }
        __syncthreads();
        const float s0 = red[slot][0][0] + red[slot][0][1] +
                         red[slot][0][2] + red[slot][0][3];
        const float s1 = red[slot][1][0] + red[slot][1][1] +
                         red[slot][1][2] + red[slot][1][3];

        float4 n0, n1;
        n0.x = fmaf(xv0.x, s0, v0.x) + b4.x;
        n0.y = fmaf(xv0.y, s0, v0.y) + b4.y;
        n0.z = fmaf(xv0.z, s0, v0.z) + b4.z;
        n0.w = fmaf(xv0.w, s0, v0.w) + b4.w;
        n1.x = fmaf(xv1.x, s1, v1.x) + b4.x;
        n1.y = fmaf(xv1.y, s1, v1.y) + b4.y;
        n1.z = fmaf(xv1.z, s1, v1.z) + b4.z;
        n1.w = fmaf(xv1.w, s1, v1.w) + b4.w;
        *(float4*)(Rout + base0) = n0;
        *(float4*)(Rout + base1) = n1;

        asum.x += n0.x + n1.x; asum.y += n0.y + n1.y;
        asum.z += n0.z + n1.z; asum.w += n0.w + n1.w;
        asq.x = fmaf(n0.x, n0.x, asq.x); asq.x = fmaf(n1.x, n1.x, asq.x);
        asq.y = fmaf(n0.y, n0.y, asq.y); asq.y = fmaf(n1.y, n1.y, asq.y);
        asq.z = fmaf(n0.z, n0.z, asq.z); asq.z = fmaf(n1.z, n1.z, asq.z);
        asq.w = fmaf(n0.w, n0.w, asq.w); asq.w = fmaf(n1.w, n1.w, asq.w);
    }
    *(float4*)(Psum + (size_t)blockIdx.x * DD + c) = asum;
    *(float4*)(Psq  + (size_t)blockIdx.x * DD + c) = asq;
}

__global__ __launch_bounds__(256) void reduce0_kernel(
    const float* __restrict__ Psum, const float* __restrict__ Psq,
    float* __restrict__ Qsum, float* __restrict__ Qsq)
{
    const int c = threadIdx.x << 2;
    const int j = blockIdx.x;
    float4 a = make_float4(0.f, 0.f, 0.f, 0.f);
    float4 q = make_float4(0.f, 0.f, 0.f, 0.f);
    #pragma unroll
    for (int k = 0; k < RED0; ++k) {
        const size_t off = (size_t)(j * RED0 + k) * DD + c;
        const float4 ps = *(const float4*)(Psum + off);
        const float4 pq = *(const float4*)(Psq + off);
        a.x += ps.x; a.y += ps.y; a.z += ps.z; a.w += ps.w;
        q.x += pq.x; q.y += pq.y; q.z += pq.z; q.w += pq.w;
    }
    *(float4*)(Qsum + (size_t)j * DD + c) = a;
    *(float4*)(Qsq  + (size_t)j * DD + c) = q;
}

__global__ __launch_bounds__(256) void stats_kernel(
    const float* __restrict__ Qsum, const float* __restrict__ Qsq,
    float* __restrict__ scale, float* __restrict__ shift)
{
    const int d = blockIdx.x * 256 + threadIdx.x;
    float s = 0.f, q = 0.f;
    #pragma unroll 8
    for (int k = 0; k < NB1; ++k) {
        s += Qsum[k * DD + d];
        q += Qsq[k * DD + d];
    }
    const float mu  = s * (1.0f / BB);
    const float var = q * (1.0f / BB) - mu * mu;
    const float inv = rsqrtf(var + BN_EPS);
    scale[d] = inv;
    shift[d] = -mu * inv;
}

__global__ __launch_bounds__(256) void finalize_kernel(
    float* __restrict__ R,
    const float* __restrict__ scale, const float* __restrict__ shift)
{
    const size_t total = (size_t)BB * DD / 4;
    const size_t stride = (size_t)gridDim.x * blockDim.x;
    for (size_t i = (size_t)blockIdx.x * blockDim.x + threadIdx.x;
         i < total; i += stride) {
        const int c = (int)(i & (DD / 4 - 1)) << 2;
        float4 v = ((const float4*)R)[i];
        const float4 sc = *(const float4*)(scale + c);
        const float4 sh = *(const float4*)(shift + c);
        v.x = fmaf(v.x, sc.x, sh.x);
        v.y = fmaf(v.y, sc.y, sh.y);
        v.z = fmaf(v.z, sc.z, sh.z);
        v.w = fmaf(v.w, sc.w, sh.w);
        ((float4*)R)[i] = v;
    }
}

extern "C" void kernel_launch(void* const* d_in, const int* in_sizes, int n_in,
                              void* d_out, int out_size, void* d_ws, size_t ws_size,
                              hipStream_t stream) {
    const float* x  = (const float*)d_in[0];
    const float* ww = (const float*)d_in[1];
    const float* wb = (const float*)d_in[2];
    float* out = (float*)d_out;
    float* ws  = (float*)d_ws;

    // Shared ws layout (fallback needs the larger sizes; coop uses a prefix).
    float* Psum  = ws;                           // 1024 * D
    float* Psq   = Psum + (size_t)ABLK * DD;     // 1024 * D
    float* Qsum  = Psq  + (size_t)ABLK * DD;     // 64 * D
    float* Qsq   = Qsum + (size_t)NB1 * DD;      // 64 * D
    float* scale = Qsq  + (size_t)NB1 * DD;      // D
    float* shift = scale + DD;                   // D

    void* args[] = {(void*)&x, (void*)&ww, (void*)&wb, (void*)&out,
                    (void*)&Psum, (void*)&Psq, (void*)&scale, (void*)&shift};
    hipError_t err = hipLaunchCooperativeKernel(
        (const void*)crossnet_coop, dim3(CGRID), dim3(CTPB), args, 0, stream);

    if (err != hipSuccess) {
        (void)hipGetLastError();  // clear error state; take the proven path
        for (int l = 0; l < NL; ++l) {
            const float* w = ww + (size_t)l * DD;
            const float* b = wb + (size_t)l * DD;
            if (l == 0) {
                layer_kernel<true><<<ABLK, 256, 0, stream>>>(
                    x, x, out, w, b, scale, shift, Psum, Psq);
            } else {
                layer_kernel<false><<<ABLK, 256, 0, stream>>>(
                    x, out, out, w, b, scale, shift, Psum, Psq);
            }
            reduce0_kernel<<<NB1, 256, 0, stream>>>(Psum, Psq, Qsum, Qsq);
            stats_kernel<<<DD / 256, 256, 0, stream>>>(Qsum, Qsq, scale, shift);
        }
        finalize_kernel<<<2048, 256, 0, stream>>>(out, scale, shift);
    }
}

// Round 4
// 847.652 us; speedup vs baseline: 1.0021x; 1.0021x over previous
//
#include <hip/hip_runtime.h>
#include <hip/hip_cooperative_groups.h>

namespace cg = cooperative_groups;

// CrossNet fused: B=16384, D=1024, 4 layers of
//   s = res.w ; res = res + x0*s + b ; res = BN_batch(res)
//
// ONE cooperative kernel, res resident in VGPRs across all 4 layers.
//  - 256 blocks x 512 threads (1 block/CU; co-residency trivially satisfied).
//    Block = 2 halves x 256 col-threads; a half owns 32 rows, thread owns
//    cols [4t,4t+4). res[32] float4 = 128 VGPRs.
//  - R3 lesson: __launch_bounds__(512,2) made the compiler cap VGPRs at 128
//    (2nd arg treated as blocks/CU -> 4 waves/EU -> 512/4) and res spilled to
//    scratch (887MB of FETCH+WRITE, 1.1TB/s). Fix: __launch_bounds__(512)
//    only — the HW caps a 512-thread block at 256 VGPRs anyway — and force
//    full unrolling of every loop that indexes res[].
//  - BN carried as lazy per-column (scale,shift), applied in-register.
//  - Stats: per-half partials (512,D) -> grid.sync -> 64 blocks reduce ->
//    grid.sync. 2 grid syncs/layer.
// Fallback (if cooperative launch rejected): verified R1 multi-kernel path.

#define BB 16384
#define DD 1024
#define NL 4
#define BN_EPS 1e-5f

// ---------------- cooperative fused path ----------------
constexpr int CGRID = 256;
constexpr int CTPB  = 512;           // 2 halves x 256 col-threads
constexpr int CRPB  = BB / CGRID;    // 64 rows per block
constexpr int CRPT  = CRPB / 2;      // 32 rows per half
constexpr int GRP   = 8;             // rows per dot-reduce batch
constexpr int NGRP  = CRPT / GRP;    // 4
constexpr int PROWS = CGRID * 2;     // 512 partial-stat rows

__global__ __launch_bounds__(CTPB) void crossnet_coop(
    const float* __restrict__ x,     // (B,D)
    const float* __restrict__ ww,    // (NL,D)
    const float* __restrict__ wb,    // (NL,D)
    float* __restrict__ out,         // (B,D)
    float* __restrict__ Psum,        // (PROWS,D) ws
    float* __restrict__ Psq,         // (PROWS,D) ws
    float* __restrict__ scale,       // (D) ws
    float* __restrict__ shift)       // (D) ws
{
    cg::grid_group grid = cg::this_grid();
    __shared__ float red[2][GRP][8];   // [slot][row][wave]
    __shared__ float sA[32][16];
    __shared__ float sQ[32][16];

    const int t    = threadIdx.x;
    const int lane = t & 63;
    const int wv   = t >> 6;           // wave 0..7
    const int half = wv >> 2;          // 0 or 1 (wave fully inside a half)
    const int c    = (t & 255) << 2;   // this thread's 4 columns
    const int b    = blockIdx.x;
    const int r0   = b * CRPB + half * CRPT;

    // res lives in registers for the entire network. Every loop indexing it
    // below is fully unrolled (compile-time indices => VGPRs, not scratch).
    float4 res[CRPT];
    #pragma unroll
    for (int r = 0; r < CRPT; ++r)
        res[r] = *(const float4*)(x + (size_t)(r0 + r) * DD + c);

    float4 sc4 = make_float4(1.f, 1.f, 1.f, 1.f);
    float4 sh4 = make_float4(0.f, 0.f, 0.f, 0.f);

    for (int l = 0; l < NL; ++l) {
        const float4 w4 = *(const float4*)(ww + (size_t)l * DD + c);
        const float4 b4 = *(const float4*)(wb + (size_t)l * DD + c);

        if (l > 0) {
            #pragma unroll
            for (int r = 0; r < CRPT; ++r) {
                res[r].x = fmaf(res[r].x, sc4.x, sh4.x);
                res[r].y = fmaf(res[r].y, sc4.y, sh4.y);
                res[r].z = fmaf(res[r].z, sc4.z, sh4.z);
                res[r].w = fmaf(res[r].w, sc4.w, sh4.w);
            }
        }

        float4 asum = make_float4(0.f, 0.f, 0.f, 0.f);
        float4 asq  = make_float4(0.f, 0.f, 0.f, 0.f);

        #pragma unroll
        for (int g = 0; g < NGRP; ++g) {
            float4 xg[GRP];
            if (l > 0) {
                #pragma unroll
                for (int j = 0; j < GRP; ++j)
                    xg[j] = *(const float4*)(x + (size_t)(r0 + g * GRP + j) * DD + c);
            }

            float p[GRP];
            #pragma unroll
            for (int j = 0; j < GRP; ++j) {
                const float4 v = res[g * GRP + j];
                p[j] = v.x * w4.x + v.y * w4.y + v.z * w4.z + v.w * w4.w;
            }
            #pragma unroll
            for (int off = 32; off; off >>= 1) {
                #pragma unroll
                for (int j = 0; j < GRP; ++j)
                    p[j] += __shfl_down(p[j], off, 64);
            }
            const int slot = g & 1;
            if (lane == 0) {
                #pragma unroll
                for (int j = 0; j < GRP; ++j) red[slot][j][wv] = p[j];
            }
            __syncthreads();

            const int w0 = half << 2;  // my half's 4 waves
            #pragma unroll
            for (int j = 0; j < GRP; ++j) {
                const float s = red[slot][j][w0] + red[slot][j][w0 + 1] +
                                red[slot][j][w0 + 2] + red[slot][j][w0 + 3];
                const float4 v  = res[g * GRP + j];
                const float4 xv = (l == 0) ? v : xg[j];
                float4 n;
                n.x = fmaf(xv.x, s, v.x) + b4.x;
                n.y = fmaf(xv.y, s, v.y) + b4.y;
                n.z = fmaf(xv.z, s, v.z) + b4.z;
                n.w = fmaf(xv.w, s, v.w) + b4.w;
                res[g * GRP + j] = n;
                asum.x += n.x; asum.y += n.y; asum.z += n.z; asum.w += n.w;
                asq.x = fmaf(n.x, n.x, asq.x);
                asq.y = fmaf(n.y, n.y, asq.y);
                asq.z = fmaf(n.z, n.z, asq.z);
                asq.w = fmaf(n.w, n.w, asq.w);
            }
        }

        const int prow = (b << 1) + half;
        *(float4*)(Psum + (size_t)prow * DD + c) = asum;
        *(float4*)(Psq  + (size_t)prow * DD + c) = asq;
        __threadfence();
        grid.sync();

        // 64 blocks: block b handles columns [16b, 16b+16) over 512 partials.
        if (b < 64) {
            const int cl  = (b << 4) + (t & 15);
            const int seg = t >> 4;                    // 0..31
            float s = 0.f, q = 0.f;
            #pragma unroll
            for (int r = seg * (PROWS / 32); r < (seg + 1) * (PROWS / 32); ++r) {
                s += Psum[(size_t)r * DD + cl];
                q += Psq[(size_t)r * DD + cl];
            }
            sA[seg][t & 15] = s;
            sQ[seg][t & 15] = q;
            __syncthreads();
            if (t < 16) {
                float ss = 0.f, qq = 0.f;
                #pragma unroll
                for (int k = 0; k < 32; ++k) { ss += sA[k][t]; qq += sQ[k][t]; }
                const float mu  = ss * (1.0f / BB);
                const float var = qq * (1.0f / BB) - mu * mu;
                const float inv = rsqrtf(var + BN_EPS);
                scale[(b << 4) + t] = inv;
                shift[(b << 4) + t] = -mu * inv;
            }
            __threadfence();
        }
        grid.sync();

        sc4 = *(const float4*)(scale + c);
        sh4 = *(const float4*)(shift + c);
    }

    #pragma unroll
    for (int r = 0; r < CRPT; ++r) {
        float4 v = res[r];
        v.x = fmaf(v.x, sc4.x, sh4.x);
        v.y = fmaf(v.y, sc4.y, sh4.y);
        v.z = fmaf(v.z, sc4.z, sh4.z);
        v.w = fmaf(v.w, sc4.w, sh4.w);
        *(float4*)(out + (size_t)(r0 + r) * DD + c) = v;
    }
}

// ---------------- fallback multi-kernel path (verified in R1) ----------------
constexpr int ABLK = 1024;
constexpr int ROWS_PER_BLK = BB / ABLK;
constexpr int NB1 = 64;
constexpr int RED0 = ABLK / NB1;

template <bool FIRST>
__global__ __launch_bounds__(256) void layer_kernel(
    const float* __restrict__ x0, const float* Rin, float* Rout,
    const float* __restrict__ w, const float* __restrict__ bias,
    const float* __restrict__ scale, const float* __restrict__ shift,
    float* __restrict__ Psum, float* __restrict__ Psq)
{
    __shared__ float red[2][2][4];
    const int tid  = threadIdx.x;
    const int lane = tid & 63;
    const int wv   = tid >> 6;
    const int c    = tid << 2;

    const float4 w4 = *(const float4*)(w + c);
    const float4 b4 = *(const float4*)(bias + c);
    float4 sc4, sh4;
    if (FIRST) {
        sc4 = make_float4(1.f, 1.f, 1.f, 1.f);
        sh4 = make_float4(0.f, 0.f, 0.f, 0.f);
    } else {
        sc4 = *(const float4*)(scale + c);
        sh4 = *(const float4*)(shift + c);
    }

    float4 asum = make_float4(0.f, 0.f, 0.f, 0.f);
    float4 asq  = make_float4(0.f, 0.f, 0.f, 0.f);
    const int r0 = blockIdx.x * ROWS_PER_BLK;

    for (int it = 0; it < ROWS_PER_BLK / 2; ++it) {
        const int r = r0 + it * 2;
        const size_t base0 = (size_t)r * DD + c;
        const size_t base1 = base0 + DD;
        float4 v0 = *(const float4*)(Rin + base0);
        float4 v1 = *(const float4*)(Rin + base1);
        float4 xv0, xv1;
        if (!FIRST) {
            xv0 = *(const float4*)(x0 + base0);
            xv1 = *(const float4*)(x0 + base1);
        }
        v0.x = fmaf(v0.x, sc4.x, sh4.x); v0.y = fmaf(v0.y, sc4.y, sh4.y);
        v0.z = fmaf(v0.z, sc4.z, sh4.z); v0.w = fmaf(v0.w, sc4.w, sh4.w);
        v1.x = fmaf(v1.x, sc4.x, sh4.x); v1.y = fmaf(v1.y, sc4.y, sh4.y);
        v1.z = fmaf(v1.z, sc4.z, sh4.z); v1.w = fmaf(v1.w, sc4.w, sh4.w);
        if (FIRST) { xv0 = v0; xv1 = v1; }

        float p0 = v0.x * w4.x + v0.y * w4.y + v0.z * w4.z + v0.w * w4.w;
        float p1 = v1.x * w4.x + v1.y * w4.y + v1.z * w4.z + v1.w * w4.w;
        #pragma unroll
        for (int off = 32; off; off >>= 1) {
            p0 += __shfl_down(p0, off, 64);
            p1 += __shfl_down(p1, off, 64);
        }
        const int slot = it & 1;
        if (lane == 0) { red[slot][0][wv] = p0; red[slot][1][wv] = p1; }
        __syncthreads();
        const float s0 = red[slot][0][0] + red[slot][0][1] +
                         red[slot][0][2] + red[slot][0][3];
        const float s1 = red[slot][1][0] + red[slot][1][1] +
                         red[slot][1][2] + red[slot][1][3];

        float4 n0, n1;
        n0.x = fmaf(xv0.x, s0, v0.x) + b4.x;
        n0.y = fmaf(xv0.y, s0, v0.y) + b4.y;
        n0.z = fmaf(xv0.z, s0, v0.z) + b4.z;
        n0.w = fmaf(xv0.w, s0, v0.w) + b4.w;
        n1.x = fmaf(xv1.x, s1, v1.x) + b4.x;
        n1.y = fmaf(xv1.y, s1, v1.y) + b4.y;
        n1.z = fmaf(xv1.z, s1, v1.z) + b4.z;
        n1.w = fmaf(xv1.w, s1, v1.w) + b4.w;
        *(float4*)(Rout + base0) = n0;
        *(float4*)(Rout + base1) = n1;

        asum.x += n0.x + n1.x; asum.y += n0.y + n1.y;
        asum.z += n0.z + n1.z; asum.w += n0.w + n1.w;
        asq.x = fmaf(n0.x, n0.x, asq.x); asq.x = fmaf(n1.x, n1.x, asq.x);
        asq.y = fmaf(n0.y, n0.y, asq.y); asq.y = fmaf(n1.y, n1.y, asq.y);
        asq.z = fmaf(n0.z, n0.z, asq.z); asq.z = fmaf(n1.z, n1.z, asq.z);
        asq.w = fmaf(n0.w, n0.w, asq.w); asq.w = fmaf(n1.w, n1.w, asq.w);
    }
    *(float4*)(Psum + (size_t)blockIdx.x * DD + c) = asum;
    *(float4*)(Psq  + (size_t)blockIdx.x * DD + c) = asq;
}

__global__ __launch_bounds__(256) void reduce0_kernel(
    const float* __restrict__ Psum, const float* __restrict__ Psq,
    float* __restrict__ Qsum, float* __restrict__ Qsq)
{
    const int c = threadIdx.x << 2;
    const int j = blockIdx.x;
    float4 a = make_float4(0.f, 0.f, 0.f, 0.f);
    float4 q = make_float4(0.f, 0.f, 0.f, 0.f);
    #pragma unroll
    for (int k = 0; k < RED0; ++k) {
        const size_t off = (size_t)(j * RED0 + k) * DD + c;
        const float4 ps = *(const float4*)(Psum + off);
        const float4 pq = *(const float4*)(Psq + off);
        a.x += ps.x; a.y += ps.y; a.z += ps.z; a.w += ps.w;
        q.x += pq.x; q.y += pq.y; q.z += pq.z; q.w += pq.w;
    }
    *(float4*)(Qsum + (size_t)j * DD + c) = a;
    *(float4*)(Qsq  + (size_t)j * DD + c) = q;
}

__global__ __launch_bounds__(256) void stats_kernel(
    const float* __restrict__ Qsum, const float* __restrict__ Qsq,
    float* __restrict__ scale, float* __restrict__ shift)
{
    const int d = blockIdx.x * 256 + threadIdx.x;
    float s = 0.f, q = 0.f;
    #pragma unroll 8
    for (int k = 0; k < NB1; ++k) {
        s += Qsum[k * DD + d];
        q += Qsq[k * DD + d];
    }
    const float mu  = s * (1.0f / BB);
    const float var = q * (1.0f / BB) - mu * mu;
    const float inv = rsqrtf(var + BN_EPS);
    scale[d] = inv;
    shift[d] = -mu * inv;
}

__global__ __launch_bounds__(256) void finalize_kernel(
    float* __restrict__ R,
    const float* __restrict__ scale, const float* __restrict__ shift)
{
    const size_t total = (size_t)BB * DD / 4;
    const size_t stride = (size_t)gridDim.x * blockDim.x;
    for (size_t i = (size_t)blockIdx.x * blockDim.x + threadIdx.x;
         i < total; i += stride) {
        const int c = (int)(i & (DD / 4 - 1)) << 2;
        float4 v = ((const float4*)R)[i];
        const float4 sc = *(const float4*)(scale + c);
        const float4 sh = *(const float4*)(shift + c);
        v.x = fmaf(v.x, sc.x, sh.x);
        v.y = fmaf(v.y, sc.y, sh.y);
        v.z = fmaf(v.z, sc.z, sh.z);
        v.w = fmaf(v.w, sc.w, sh.w);
        ((float4*)R)[i] = v;
    }
}

extern "C" void kernel_launch(void* const* d_in, const int* in_sizes, int n_in,
                              void* d_out, int out_size, void* d_ws, size_t ws_size,
                              hipStream_t stream) {
    const float* x  = (const float*)d_in[0];
    const float* ww = (const float*)d_in[1];
    const float* wb = (const float*)d_in[2];
    float* out = (float*)d_out;
    float* ws  = (float*)d_ws;

    // Shared ws layout (fallback needs the larger sizes; coop uses a prefix).
    float* Psum  = ws;                           // 1024 * D
    float* Psq   = Psum + (size_t)ABLK * DD;     // 1024 * D
    float* Qsum  = Psq  + (size_t)ABLK * DD;     // 64 * D
    float* Qsq   = Qsum + (size_t)NB1 * DD;      // 64 * D
    float* scale = Qsq  + (size_t)NB1 * DD;      // D
    float* shift = scale + DD;                   // D

    void* args[] = {(void*)&x, (void*)&ww, (void*)&wb, (void*)&out,
                    (void*)&Psum, (void*)&Psq, (void*)&scale, (void*)&shift};
    hipError_t err = hipLaunchCooperativeKernel(
        (const void*)crossnet_coop, dim3(CGRID), dim3(CTPB), args, 0, stream);

    if (err != hipSuccess) {
        (void)hipGetLastError();  // clear error state; take the proven path
        for (int l = 0; l < NL; ++l) {
            const float* w = ww + (size_t)l * DD;
            const float* b = wb + (size_t)l * DD;
            if (l == 0) {
                layer_kernel<true><<<ABLK, 256, 0, stream>>>(
                    x, x, out, w, b, scale, shift, Psum, Psq);
            } else {
                layer_kernel<false><<<ABLK, 256, 0, stream>>>(
                    x, out, out, w, b, scale, shift, Psum, Psq);
            }
            reduce0_kernel<<<NB1, 256, 0, stream>>>(Psum, Psq, Qsum, Qsq);
            stats_kernel<<<DD / 256, 256, 0, stream>>>(Qsum, Qsq, scale, shift);
        }
        finalize_kernel<<<2048, 256, 0, stream>>>(out, scale, shift);
    }
}